// Round 2
// baseline (41769.318 us; speedup 1.0000x reference)
//
#include <hip/hip_runtime.h>

// Problem constants
#define BB 256     // batch
#define SS 1024    // seq len
#define II 64      // input dim
#define HH 256     // hidden
#define OO 24      // output dim

#define NG 16      // groups (each owns 16 batch rows)
#define NP 16      // parts per group (each owns 64 of 1024 z-cols = 16 h-dims)
#define BT 16      // batch tile per group

__device__ __forceinline__ float fsig(float x)  { return 1.0f / (1.0f + __expf(-x)); }
__device__ __forceinline__ float ftanh(float x) { return 1.0f - 2.0f / (__expf(2.0f * x) + 1.0f); }

// ---------------------------------------------------------------------------
// Fused xW + LSTM recurrence + attention scores + online-softmax context.
// grid = 256 blocks (16 groups x 16 parts), block = 256 threads.
// part p = blockIdx>>4, group g = blockIdx&15 -> blk%8 == g%8: all 16 parts
// of a group land on one XCD under the round-robin dispatch heuristic.
// LDS = 125 KB -> 1 block/CU -> all 256 blocks co-resident (spin-sync safe).
// Workspace: < 1 MB total (hg exchange + score partials ring + ctx + counters).
// ---------------------------------------------------------------------------
__global__ __launch_bounds__(256, 1)
void lstm_fused_kernel(const float* __restrict__ x,  const float* __restrict__ Wi,
                       const float* __restrict__ Wh, const float* __restrict__ bias,
                       const float* __restrict__ aW, const float* __restrict__ ab,
                       const float* __restrict__ av,
                       float* __restrict__ hg, float* __restrict__ sp,
                       float* __restrict__ ctxg, unsigned int* __restrict__ cnt)
{
    __shared__ float whs[256][64];    // Wh slice [k][local col]          64.0 KB
    __shared__ float h4[256][20];     // h(t-1) [k][batch] (pad 16->20)   20.0 KB
    __shared__ float hT[BT][260];     // h(t-1) transposed [batch][k]     16.6 KB
    __shared__ float waT[BT][268];    // attn_W cols (transposed)         17.2 KB
    __shared__ float z_lds[BT][64];   // z slice [batch][local col]        4.0 KB
    __shared__ float xs[BT][64];      // x rows for current t              4.0 KB

    const int tid = threadIdx.x;
    const int p = blockIdx.x >> 4;    // part  0..15
    const int g = blockIdx.x & 15;    // group 0..15
    const int b0 = g * BT;

    // z-phase mapping: col c = q*16+r -> global col q*256 + p*16 + r
    const int c  = tid & 63;
    const int bq = tid >> 6;          // batch quad (wave-uniform)
    const int gcol = (c >> 4) * HH + p * 16 + (c & 15);

    // Wi column resident in registers
    float wi[II];
    #pragma unroll
    for (int k = 0; k < II; ++k) wi[k] = Wi[k * (4 * HH) + gcol];
    const float bc = bias[gcol];

    // stage Wh slice (once)
    for (int idx = tid; idx < 256 * 64; idx += 256) {
        int k = idx >> 6, cc = idx & 63;
        whs[k][cc] = Wh[k * (4 * HH) + ((cc >> 4) * HH + p * 16 + (cc & 15))];
    }
    // stage attn_W cols p*16..p*16+15, transposed (once)
    for (int idx = tid; idx < 256 * 16; idx += 256) {
        int k = idx >> 4, j = idx & 15;
        waT[j][k] = aW[k * HH + p * 16 + j];
    }

    // gate/energy mapping: (batch sb, dim/col sj)
    const int sb = tid >> 4;
    const int sj = tid & 15;
    const float vj  = av[p * 16 + sj];
    const float abj = ab[p * 16 + sj];
    const int hdim  = p * 16 + sj;

    float c_state = 0.0f;
    float h1 = 0.0f, h2 = 0.0f;            // own-h history: h(t-1), h(t-2)
    float m_run = -1.0e30f, l_run = 0.0f, ctx = 0.0f;
    int dead = 0;                          // spin trip-wire (tid0 only)

    unsigned int* mycnt = cnt + g * (SS + 1);
    float* mysp = sp + (size_t)g * (4 * HH);   // score-partials ring [4][256]

    for (int t = 0; t < SS; ++t) {
        // ---- stage x(t): 16 rows x 64
        {
            int b = tid >> 4, k0 = (tid & 15) << 2;
            float4 xv = *(const float4*)(x + ((size_t)(b0 + b) * SS + t) * II + k0);
            *(float4*)&xs[b][k0] = xv;
        }
        __syncthreads();

        // ---- acc = bias + x @ Wi
        float acc0 = bc, acc1 = bc, acc2 = bc, acc3 = bc;
        #pragma unroll
        for (int j = 0; j < 4; ++j) {
            float s = 0.0f;
            #pragma unroll
            for (int k = 0; k < II; k += 4) {
                float4 xv = *(const float4*)&xs[bq * 4 + j][k];
                s = fmaf(xv.x, wi[k],     s);
                s = fmaf(xv.y, wi[k + 1], s);
                s = fmaf(xv.z, wi[k + 2], s);
                s = fmaf(xv.w, wi[k + 3], s);
            }
            if      (j == 0) acc0 += s;
            else if (j == 1) acc1 += s;
            else if (j == 2) acc2 += s;
            else             acc3 += s;
        }

        if (t > 0) {
            // ---- wait for all parts to publish h(t-1) (+ score partials t-2)
            if (tid == 0 && !dead) {
                unsigned int it = 0;
                while (atomicAdd(&mycnt[t - 1], 0u) < (unsigned)NP) {
                    __builtin_amdgcn_s_sleep(2);
                    if (++it > (1u << 24)) { dead = 1; break; }
                }
            }
            __syncthreads();
            __threadfence();   // acquire

            // ---- load h(t-1): thread tid owns k-row tid (16 floats)
            const float* hp = hg + ((((size_t)((t - 1) & 1)) * NG + g) * HH + tid) * BT;
            float4 a0 = *(const float4*)(hp + 0);
            float4 a1 = *(const float4*)(hp + 4);
            float4 a2 = *(const float4*)(hp + 8);
            float4 a3 = *(const float4*)(hp + 12);

            // ---- online-softmax update for time t-2 (score now complete)
            if (t > 1) {
                float spv = mysp[((t - 2) & 3) * HH + tid];       // [b][p] layout
                spv += __shfl_xor(spv, 1); spv += __shfl_xor(spv, 2);
                spv += __shfl_xor(spv, 4); spv += __shfl_xor(spv, 8);
                float m_new = fmaxf(m_run, spv);
                float scale = __expf(m_run - m_new);
                float w     = __expf(spv - m_new);
                l_run = l_run * scale + w;
                ctx   = ctx * scale + w * h2;    // h2 == h(t-2) own value
                m_run = m_new;
            }

            *(float4*)&h4[tid][0]  = a0;
            *(float4*)&h4[tid][4]  = a1;
            *(float4*)&h4[tid][8]  = a2;
            *(float4*)&h4[tid][12] = a3;
            hT[0][tid]  = a0.x; hT[1][tid]  = a0.y; hT[2][tid]  = a0.z; hT[3][tid]  = a0.w;
            hT[4][tid]  = a1.x; hT[5][tid]  = a1.y; hT[6][tid]  = a1.z; hT[7][tid]  = a1.w;
            hT[8][tid]  = a2.x; hT[9][tid]  = a2.y; hT[10][tid] = a2.z; hT[11][tid] = a2.w;
            hT[12][tid] = a3.x; hT[13][tid] = a3.y; hT[14][tid] = a3.z; hT[15][tid] = a3.w;
            __syncthreads();

            // ---- z += h(t-1) @ Wh
            #pragma unroll 8
            for (int k = 0; k < HH; ++k) {
                float wh = whs[k][c];
                float4 hv = *(const float4*)&h4[k][bq * 4];
                acc0 = fmaf(wh, hv.x, acc0);
                acc1 = fmaf(wh, hv.y, acc1);
                acc2 = fmaf(wh, hv.z, acc2);
                acc3 = fmaf(wh, hv.w, acc3);
            }

            // ---- energy/score partials for time t-1 (uses hT = h(t-1))
            float e = abj;
            #pragma unroll 4
            for (int k = 0; k < HH; k += 4) {
                float4 hv = *(const float4*)&hT[sb][k];
                float4 wv = *(const float4*)&waT[sj][k];
                e = fmaf(hv.x, wv.x, e); e = fmaf(hv.y, wv.y, e);
                e = fmaf(hv.z, wv.z, e); e = fmaf(hv.w, wv.w, e);
            }
            float scp = vj * ftanh(e);
            scp += __shfl_xor(scp, 1); scp += __shfl_xor(scp, 2);
            scp += __shfl_xor(scp, 4); scp += __shfl_xor(scp, 8);
            if (sj == 0) mysp[((t - 1) & 3) * HH + sb * 16 + p] = scp;
        }

        // ---- gates
        z_lds[bq * 4 + 0][c] = acc0;
        z_lds[bq * 4 + 1][c] = acc1;
        z_lds[bq * 4 + 2][c] = acc2;
        z_lds[bq * 4 + 3][c] = acc3;
        __syncthreads();

        float zi = z_lds[sb][sj];
        float zf = z_lds[sb][16 + sj];
        float zg = z_lds[sb][32 + sj];
        float zo = z_lds[sb][48 + sj];
        float ig = fsig(zi), fg = fsig(zf), gv = ftanh(zg), og = fsig(zo);
        c_state = fg * c_state + ig * gv;
        float h = og * ftanh(c_state);
        h2 = h1; h1 = h;

        hg[((((size_t)(t & 1)) * NG + g) * HH + hdim) * BT + sb] = h;

        __threadfence();   // release
        __syncthreads();
        if (tid == 0) atomicAdd(&mycnt[t], 1u);
    }

    // ---- epilogue A: score partials for time SS-1, update for SS-2
    {
        if (tid == 0 && !dead) {
            unsigned int it = 0;
            while (atomicAdd(&mycnt[SS - 1], 0u) < (unsigned)NP) {
                __builtin_amdgcn_s_sleep(2);
                if (++it > (1u << 24)) { dead = 1; break; }
            }
        }
        __syncthreads();
        __threadfence();

        const float* hp = hg + ((((size_t)((SS - 1) & 1)) * NG + g) * HH + tid) * BT;
        float4 a0 = *(const float4*)(hp + 0);
        float4 a1 = *(const float4*)(hp + 4);
        float4 a2 = *(const float4*)(hp + 8);
        float4 a3 = *(const float4*)(hp + 12);

        {   // update time SS-2 with h2 = h(SS-2)
            float spv = mysp[((SS - 2) & 3) * HH + tid];
            spv += __shfl_xor(spv, 1); spv += __shfl_xor(spv, 2);
            spv += __shfl_xor(spv, 4); spv += __shfl_xor(spv, 8);
            float m_new = fmaxf(m_run, spv);
            float scale = __expf(m_run - m_new);
            float w     = __expf(spv - m_new);
            l_run = l_run * scale + w;
            ctx   = ctx * scale + w * h2;
            m_run = m_new;
        }

        hT[0][tid]  = a0.x; hT[1][tid]  = a0.y; hT[2][tid]  = a0.z; hT[3][tid]  = a0.w;
        hT[4][tid]  = a1.x; hT[5][tid]  = a1.y; hT[6][tid]  = a1.z; hT[7][tid]  = a1.w;
        hT[8][tid]  = a2.x; hT[9][tid]  = a2.y; hT[10][tid] = a2.z; hT[11][tid] = a2.w;
        hT[12][tid] = a3.x; hT[13][tid] = a3.y; hT[14][tid] = a3.z; hT[15][tid] = a3.w;
        h2 = h1;           // h(SS-1) for epilogue B
        __syncthreads();

        float e = abj;
        #pragma unroll 4
        for (int k = 0; k < HH; k += 4) {
            float4 hv = *(const float4*)&hT[sb][k];
            float4 wv = *(const float4*)&waT[sj][k];
            e = fmaf(hv.x, wv.x, e); e = fmaf(hv.y, wv.y, e);
            e = fmaf(hv.z, wv.z, e); e = fmaf(hv.w, wv.w, e);
        }
        float scp = vj * ftanh(e);
        scp += __shfl_xor(scp, 1); scp += __shfl_xor(scp, 2);
        scp += __shfl_xor(scp, 4); scp += __shfl_xor(scp, 8);
        if (sj == 0) mysp[((SS - 1) & 3) * HH + sb * 16 + p] = scp;

        __threadfence();
        __syncthreads();
        if (tid == 0) atomicAdd(&mycnt[SS], 1u);
    }

    // ---- epilogue B: update for SS-1, write normalized context
    {
        if (tid == 0 && !dead) {
            unsigned int it = 0;
            while (atomicAdd(&mycnt[SS], 0u) < (unsigned)NP) {
                __builtin_amdgcn_s_sleep(2);
                if (++it > (1u << 24)) { dead = 1; break; }
            }
        }
        __syncthreads();
        __threadfence();

        float spv = mysp[((SS - 1) & 3) * HH + tid];
        spv += __shfl_xor(spv, 1); spv += __shfl_xor(spv, 2);
        spv += __shfl_xor(spv, 4); spv += __shfl_xor(spv, 8);
        float m_new = fmaxf(m_run, spv);
        float scale = __expf(m_run - m_new);
        float w     = __expf(spv - m_new);
        l_run = l_run * scale + w;
        ctx   = ctx * scale + w * h2;   // h2 == h(SS-1)

        ctxg[(size_t)(b0 + sb) * HH + hdim] = ctx / l_run;
    }
}

// ---------------------------------------------------------------------------
// out[b] = ctx[b] @ fc_W + fc_b     (3 MFLOP total -- trivial)
// ---------------------------------------------------------------------------
__global__ __launch_bounds__(64)
void finalize_kernel(const float* __restrict__ ctxg, const float* __restrict__ fcW,
                     const float* __restrict__ fcb, float* __restrict__ out)
{
    __shared__ float cs[HH];
    const int b = blockIdx.x, tid = threadIdx.x;   // 64 threads
    *(float4*)&cs[tid * 4] = *(const float4*)&ctxg[(size_t)b * HH + tid * 4];
    __syncthreads();
    if (tid < OO) {
        float a = fcb[tid];
        #pragma unroll 8
        for (int d = 0; d < HH; ++d) a = fmaf(cs[d], fcW[d * OO + tid], a);
        out[b * OO + tid] = a;
    }
}

// ---------------------------------------------------------------------------
extern "C" void kernel_launch(void* const* d_in, const int* in_sizes, int n_in,
                              void* d_out, int out_size, void* d_ws, size_t ws_size,
                              hipStream_t stream)
{
    const float* x      = (const float*)d_in[0];
    const float* Wi     = (const float*)d_in[1];
    const float* Wh     = (const float*)d_in[2];
    const float* bias   = (const float*)d_in[3];
    const float* attn_W = (const float*)d_in[4];
    const float* attn_b = (const float*)d_in[5];
    const float* v      = (const float*)d_in[6];
    const float* fc_W   = (const float*)d_in[7];
    const float* fc_b   = (const float*)d_in[8];
    float* out = (float*)d_out;

    // workspace: < 1 MB total
    float* ws   = (float*)d_ws;
    float* hg   = ws;                                  // 2*NG*HH*BT = 131072 floats
    float* sp   = hg + 2 * NG * HH * BT;               // NG*4*HH    =  16384 floats
    float* ctxg = sp + NG * 4 * HH;                    // BB*HH      =  65536 floats
    unsigned int* cnt = (unsigned int*)(ctxg + BB * HH);  // NG*(SS+1) uints

    hipMemsetAsync(cnt, 0, NG * (SS + 1) * sizeof(unsigned int), stream);

    lstm_fused_kernel<<<dim3(NG * NP), dim3(256), 0, stream>>>(
        x, Wi, Wh, bias, attn_W, attn_b, v, hg, sp, ctxg, cnt);
    finalize_kernel<<<dim3(BB), dim3(64), 0, stream>>>(ctxg, fc_W, fc_b, out);
}

// Round 3
// 9450.774 us; speedup vs baseline: 4.4197x; 4.4197x over previous
//
#include <hip/hip_runtime.h>

// Problem constants
#define BB 256     // batch
#define SS 1024    // seq len
#define II 64      // input dim
#define HH 256     // hidden
#define OO 24      // output dim

#define NG 16      // groups (each owns 16 batch rows)
#define NP 16      // parts per group (each owns 64 of 1024 z-cols = 16 h-dims)
#define BT 16      // batch tile per group

#define POLL_CAP (1 << 20)   // trip-wire: fail fast instead of hanging

__device__ __forceinline__ float fsig(float x)  { return 1.0f / (1.0f + __expf(-x)); }
__device__ __forceinline__ float ftanh(float x) { return 1.0f - 2.0f / (__expf(2.0f * x) + 1.0f); }

__device__ __forceinline__ float coh_ld(const float* p) {
    return __hip_atomic_load(p, __ATOMIC_RELAXED, __HIP_MEMORY_SCOPE_AGENT);
}
__device__ __forceinline__ void coh_st(float* p, float v) {
    __hip_atomic_store(p, v, __ATOMIC_RELAXED, __HIP_MEMORY_SCOPE_AGENT);
}

// ---------------------------------------------------------------------------
// Fused xW + LSTM recurrence + attention scores + online-softmax context.
// grid = 256 blocks (16 groups x 16 parts), block = 256 threads.
// Cross-part exchange: fine-grained coherent (sc0 sc1) loads/stores only —
// no __threadfence, no L2 writeback/invalidate, no RMW spins.
// Release: h stores -> s_waitcnt vmcnt(0) -> barrier -> seq-flag store.
// Acquire: 16 lanes poll 16 part-flags with plain coherent loads.
// LDS ~126 KB -> 1 block/CU -> all 256 blocks co-resident.
// ---------------------------------------------------------------------------
__global__ __launch_bounds__(256, 1)
void lstm_fused_kernel(const float* __restrict__ x,  const float* __restrict__ Wi,
                       const float* __restrict__ Wh, const float* __restrict__ bias,
                       const float* __restrict__ aW, const float* __restrict__ ab,
                       const float* __restrict__ av,
                       float* __restrict__ hg, float* __restrict__ sp,
                       float* __restrict__ ctxg, unsigned int* __restrict__ flag)
{
    __shared__ float whs[256][64];    // Wh slice [k][local col]          64.0 KB
    __shared__ float h4[256][20];     // h(t-1) [k][batch] (pad 16->20)   20.0 KB
    __shared__ float hT[BT][260];     // h(t-1) transposed [batch][k]     16.6 KB
    __shared__ float waT[BT][268];    // attn_W cols (transposed)         17.2 KB
    __shared__ float z_lds[BT][64];   // z slice [batch][local col]        4.0 KB
    __shared__ float xs[BT][64];      // x rows for current t              4.0 KB
    __shared__ float hst[256];        // h(t) staging for coalesced store  1.0 KB
    __shared__ int   sdead;

    const int tid = threadIdx.x;
    const int p = blockIdx.x >> 4;    // part  0..15
    const int g = blockIdx.x & 15;    // group 0..15
    const int b0 = g * BT;

    if (tid == 0) sdead = 0;

    // z-phase mapping: col c = q*16+r -> global col q*256 + p*16 + r
    const int c  = tid & 63;
    const int bq = tid >> 6;          // batch quad (wave-uniform)
    const int gcol = (c >> 4) * HH + p * 16 + (c & 15);

    // Wi column resident in registers
    float wi[II];
    #pragma unroll
    for (int k = 0; k < II; ++k) wi[k] = Wi[k * (4 * HH) + gcol];
    const float bc = bias[gcol];

    // stage Wh slice (once)
    for (int idx = tid; idx < 256 * 64; idx += 256) {
        int k = idx >> 6, cc = idx & 63;
        whs[k][cc] = Wh[k * (4 * HH) + ((cc >> 4) * HH + p * 16 + (cc & 15))];
    }
    // stage attn_W cols p*16..p*16+15, transposed (once)
    for (int idx = tid; idx < 256 * 16; idx += 256) {
        int k = idx >> 4, j = idx & 15;
        waT[j][k] = aW[k * HH + p * 16 + j];
    }

    // gate/energy mapping: (batch sb, dim sj)
    const int sb = tid >> 4;
    const int sj = tid & 15;
    const float vj  = av[p * 16 + sj];
    const float abj = ab[p * 16 + sj];

    // h-exchange LDS scatter mapping (coalesced global idx = j*256 + tid)
    const int kk = tid >> 4;          // == sb
    const int bb = tid & 15;          // == sj

    float c_state = 0.0f;
    float h1 = 0.0f, h2 = 0.0f;            // own-h history: h(t-1), h(t-2)
    float m_run = -1.0e30f, l_run = 0.0f, ctx = 0.0f;

    unsigned int* myflag = flag + g * NP;
    float* mysp = sp + (size_t)g * (4 * HH);   // score-partials ring [4][256]

    for (int t = 0; t < SS; ++t) {
        // ---- stage x(t): 16 rows x 64
        {
            float4 xv = *(const float4*)(x + ((size_t)(b0 + kk) * SS + t) * II + (bb << 2));
            *(float4*)&xs[kk][bb << 2] = xv;
        }
        __syncthreads();

        // ---- acc = bias + x @ Wi   (overlaps remote h publication)
        float acc0 = bc, acc1 = bc, acc2 = bc, acc3 = bc;
        #pragma unroll
        for (int j = 0; j < 4; ++j) {
            float s = 0.0f;
            #pragma unroll
            for (int k = 0; k < II; k += 4) {
                float4 xv = *(const float4*)&xs[bq * 4 + j][k];
                s = fmaf(xv.x, wi[k],     s);
                s = fmaf(xv.y, wi[k + 1], s);
                s = fmaf(xv.z, wi[k + 2], s);
                s = fmaf(xv.w, wi[k + 3], s);
            }
            if      (j == 0) acc0 += s;
            else if (j == 1) acc1 += s;
            else if (j == 2) acc2 += s;
            else             acc3 += s;
        }

        if (t > 0) {
            // ---- acquire: poll 16 part-flags (plain coherent loads, no RMW)
            if (tid < NP && !sdead) {
                int it = 0;
                while (__hip_atomic_load(&myflag[tid], __ATOMIC_RELAXED,
                                         __HIP_MEMORY_SCOPE_AGENT) < (unsigned)t) {
                    if (++it > POLL_CAP) { sdead = 1; break; }
                }
            }
            __syncthreads();

            // ---- coherent coalesced h(t-1) load: idx = j*256 + tid
            const float* hp = hg + (((size_t)((t - 1) & 1)) * NG + g) * (HH * BT);
            float a[16];
            #pragma unroll
            for (int j = 0; j < 16; ++j) a[j] = coh_ld(hp + j * 256 + tid);

            // ---- online-softmax update for time t-2 (score now complete)
            if (t > 1) {
                float spv = coh_ld(&mysp[((t - 2) & 3) * HH + tid]);   // [b][p]
                spv += __shfl_xor(spv, 1); spv += __shfl_xor(spv, 2);
                spv += __shfl_xor(spv, 4); spv += __shfl_xor(spv, 8);
                float m_new = fmaxf(m_run, spv);
                float scale = __expf(m_run - m_new);
                float w     = __expf(spv - m_new);
                l_run = l_run * scale + w;
                ctx   = ctx * scale + w * h2;    // h2 == h(t-2) own value
                m_run = m_new;
            }

            // ---- scatter to LDS: element j*256+tid -> k = j*16+kk, b = bb
            #pragma unroll
            for (int j = 0; j < 16; ++j) {
                h4[j * 16 + kk][bb] = a[j];
                hT[bb][j * 16 + kk] = a[j];
            }
            __syncthreads();

            // ---- z += h(t-1) @ Wh
            #pragma unroll 8
            for (int k = 0; k < HH; ++k) {
                float wh = whs[k][c];
                float4 hv = *(const float4*)&h4[k][bq * 4];
                acc0 = fmaf(wh, hv.x, acc0);
                acc1 = fmaf(wh, hv.y, acc1);
                acc2 = fmaf(wh, hv.z, acc2);
                acc3 = fmaf(wh, hv.w, acc3);
            }

            // ---- energy/score partials for time t-1 (uses hT = h(t-1))
            float e = abj;
            #pragma unroll 4
            for (int k = 0; k < HH; k += 4) {
                float4 hv = *(const float4*)&hT[sb][k];
                float4 wv = *(const float4*)&waT[sj][k];
                e = fmaf(hv.x, wv.x, e); e = fmaf(hv.y, wv.y, e);
                e = fmaf(hv.z, wv.z, e); e = fmaf(hv.w, wv.w, e);
            }
            float scp = vj * ftanh(e);
            scp += __shfl_xor(scp, 1); scp += __shfl_xor(scp, 2);
            scp += __shfl_xor(scp, 4); scp += __shfl_xor(scp, 8);
            if (sj == 0) coh_st(&mysp[((t - 1) & 3) * HH + sb * 16 + p], scp);
        }

        // ---- gates
        z_lds[bq * 4 + 0][c] = acc0;
        z_lds[bq * 4 + 1][c] = acc1;
        z_lds[bq * 4 + 2][c] = acc2;
        z_lds[bq * 4 + 3][c] = acc3;
        __syncthreads();

        float zi = z_lds[sb][sj];
        float zf = z_lds[sb][16 + sj];
        float zg = z_lds[sb][32 + sj];
        float zo = z_lds[sb][48 + sj];
        float ig = fsig(zi), fg = fsig(zf), gv = ftanh(zg), og = fsig(zo);
        c_state = fg * c_state + ig * gv;
        float h = og * ftanh(c_state);
        h2 = h1; h1 = h;

        // ---- publish h(t): stage in LDS, coalesced coherent store, release
        hst[sj * 16 + sb] = h;
        __syncthreads();
        {
            float* hw = hg + (((size_t)(t & 1)) * NG + g) * (HH * BT) + p * 256;
            coh_st(hw + tid, hst[tid]);
        }
        asm volatile("s_waitcnt vmcnt(0)" ::: "memory");
        __syncthreads();
        if (tid == 0)
            __hip_atomic_store(&myflag[p], (unsigned)(t + 1),
                               __ATOMIC_RELAXED, __HIP_MEMORY_SCOPE_AGENT);
    }

    // ---- epilogue A: score partials for time SS-1, update for SS-2
    {
        if (tid < NP && !sdead) {
            int it = 0;
            while (__hip_atomic_load(&myflag[tid], __ATOMIC_RELAXED,
                                     __HIP_MEMORY_SCOPE_AGENT) < (unsigned)SS) {
                if (++it > POLL_CAP) { sdead = 1; break; }
            }
        }
        __syncthreads();

        const float* hp = hg + (((size_t)((SS - 1) & 1)) * NG + g) * (HH * BT);
        float a[16];
        #pragma unroll
        for (int j = 0; j < 16; ++j) a[j] = coh_ld(hp + j * 256 + tid);

        {   // update time SS-2 with h2 = h(SS-2)
            float spv = coh_ld(&mysp[((SS - 2) & 3) * HH + tid]);
            spv += __shfl_xor(spv, 1); spv += __shfl_xor(spv, 2);
            spv += __shfl_xor(spv, 4); spv += __shfl_xor(spv, 8);
            float m_new = fmaxf(m_run, spv);
            float scale = __expf(m_run - m_new);
            float w     = __expf(spv - m_new);
            l_run = l_run * scale + w;
            ctx   = ctx * scale + w * h2;
            m_run = m_new;
        }

        #pragma unroll
        for (int j = 0; j < 16; ++j) hT[bb][j * 16 + kk] = a[j];
        h2 = h1;           // h(SS-1) for epilogue B
        __syncthreads();

        float e = abj;
        #pragma unroll 4
        for (int k = 0; k < HH; k += 4) {
            float4 hv = *(const float4*)&hT[sb][k];
            float4 wv = *(const float4*)&waT[sj][k];
            e = fmaf(hv.x, wv.x, e); e = fmaf(hv.y, wv.y, e);
            e = fmaf(hv.z, wv.z, e); e = fmaf(hv.w, wv.w, e);
        }
        float scp = vj * ftanh(e);
        scp += __shfl_xor(scp, 1); scp += __shfl_xor(scp, 2);
        scp += __shfl_xor(scp, 4); scp += __shfl_xor(scp, 8);
        if (sj == 0) coh_st(&mysp[((SS - 1) & 3) * HH + sb * 16 + p], scp);

        asm volatile("s_waitcnt vmcnt(0)" ::: "memory");
        __syncthreads();
        if (tid == 0)
            __hip_atomic_store(&myflag[p], (unsigned)(SS + 1),
                               __ATOMIC_RELAXED, __HIP_MEMORY_SCOPE_AGENT);
    }

    // ---- epilogue B: update for SS-1, write normalized context
    {
        if (tid < NP && !sdead) {
            int it = 0;
            while (__hip_atomic_load(&myflag[tid], __ATOMIC_RELAXED,
                                     __HIP_MEMORY_SCOPE_AGENT) < (unsigned)(SS + 1)) {
                if (++it > POLL_CAP) { sdead = 1; break; }
            }
        }
        __syncthreads();

        float spv = coh_ld(&mysp[((SS - 1) & 3) * HH + tid]);
        spv += __shfl_xor(spv, 1); spv += __shfl_xor(spv, 2);
        spv += __shfl_xor(spv, 4); spv += __shfl_xor(spv, 8);
        float m_new = fmaxf(m_run, spv);
        float scale = __expf(m_run - m_new);
        float w     = __expf(spv - m_new);
        l_run = l_run * scale + w;
        ctx   = ctx * scale + w * h2;   // h2 == h(SS-1)

        ctxg[(size_t)(b0 + sb) * HH + p * 16 + sj] = ctx / l_run;
    }
}

// ---------------------------------------------------------------------------
// out[b] = ctx[b] @ fc_W + fc_b     (3 MFLOP total -- trivial)
// ---------------------------------------------------------------------------
__global__ __launch_bounds__(64)
void finalize_kernel(const float* __restrict__ ctxg, const float* __restrict__ fcW,
                     const float* __restrict__ fcb, float* __restrict__ out)
{
    __shared__ float cs[HH];
    const int b = blockIdx.x, tid = threadIdx.x;   // 64 threads
    *(float4*)&cs[tid * 4] = *(const float4*)&ctxg[(size_t)b * HH + tid * 4];
    __syncthreads();
    if (tid < OO) {
        float a = fcb[tid];
        #pragma unroll 8
        for (int d = 0; d < HH; ++d) a = fmaf(cs[d], fcW[d * OO + tid], a);
        out[b * OO + tid] = a;
    }
}

// ---------------------------------------------------------------------------
extern "C" void kernel_launch(void* const* d_in, const int* in_sizes, int n_in,
                              void* d_out, int out_size, void* d_ws, size_t ws_size,
                              hipStream_t stream)
{
    const float* x      = (const float*)d_in[0];
    const float* Wi     = (const float*)d_in[1];
    const float* Wh     = (const float*)d_in[2];
    const float* bias   = (const float*)d_in[3];
    const float* attn_W = (const float*)d_in[4];
    const float* attn_b = (const float*)d_in[5];
    const float* v      = (const float*)d_in[6];
    const float* fc_W   = (const float*)d_in[7];
    const float* fc_b   = (const float*)d_in[8];
    float* out = (float*)d_out;

    // workspace: < 1 MB total
    float* ws   = (float*)d_ws;
    float* hg   = ws;                                  // 2*NG*HH*BT = 131072 floats
    float* sp   = hg + 2 * NG * HH * BT;               // NG*4*HH    =  16384 floats
    float* ctxg = sp + NG * 4 * HH;                    // BB*HH      =  65536 floats
    unsigned int* flag = (unsigned int*)(ctxg + BB * HH);  // NG*NP uints

    hipMemsetAsync(flag, 0, NG * NP * sizeof(unsigned int), stream);

    lstm_fused_kernel<<<dim3(NG * NP), dim3(256), 0, stream>>>(
        x, Wi, Wh, bias, attn_W, attn_b, v, hg, sp, ctxg, flag);
    finalize_kernel<<<dim3(BB), dim3(64), 0, stream>>>(ctxg, fc_W, fc_b, out);
}

// Round 4
// 5618.933 us; speedup vs baseline: 7.4337x; 1.6820x over previous
//
#include <hip/hip_runtime.h>

// Problem constants
#define BB 256
#define SS 1024
#define II 64
#define HH 256
#define OO 24
#define NG 16     // groups (16 batch rows each)
#define NP 16     // parts per group (64 z-cols = 16 h-dims each)
#define BT 16

typedef __attribute__((ext_vector_type(8))) short short8;
typedef __attribute__((ext_vector_type(4))) float f32x4;
typedef unsigned long long ull;

#define POLL_CAP 262144

// LDS byte offsets (single 128KB block also forces 1 block/CU)
#define A_HI 0          // h hi frags  [8 kstep][64 lane][16B]
#define A_LO 8192
#define X_HI 16384      // x frags     [2 kstep][64 lane][16B]
#define X_LO 18432
#define Z_OF 20480      // z   [gate q][reg r][lane]  f32
#define E_OF 24576      // energy partials, same layout
#define SMEM_BYTES 131072

#define MFMA(a,b,c) __builtin_amdgcn_mfma_f32_16x16x32_bf16(a,b,c,0,0,0)

__device__ __forceinline__ float fsig(float x)  { return 1.f/(1.f+__expf(-x)); }
__device__ __forceinline__ float ftanh(float x) { return 1.f - 2.f/(__expf(2.f*x)+1.f); }

__device__ __forceinline__ unsigned rne_bf16(float x){
    unsigned u = __float_as_uint(x);
    return (u + 0x7FFFu + ((u>>16)&1u)) >> 16;
}
__device__ __forceinline__ void split_bf(float x, unsigned &hi, unsigned &lo){
    hi = rne_bf16(x);
    lo = rne_bf16(x - __uint_as_float(hi<<16));
}

union U4 { unsigned u[4]; short8 s; };

__device__ __forceinline__ ull cld(const ull* p){
    return __hip_atomic_load(p, __ATOMIC_RELAXED, __HIP_MEMORY_SCOPE_AGENT);
}
__device__ __forceinline__ void cst(ull* p, ull v){
    __hip_atomic_store(p, v, __ATOMIC_RELAXED, __HIP_MEMORY_SCOPE_AGENT);
}

// ---------------------------------------------------------------------------
// Fused xW + LSTM + attention scores + online-softmax context, MFMA bf16x3.
// grid = 256 (16 groups x 16 parts), block = 256 (4 waves).
// Wave w owns gate w (z cols w*256 + p*16 + 0..15). B-fragments in registers.
// Cross-part exchange: tag-carried 8B coherent atomics (no flags, no fences).
// ---------------------------------------------------------------------------
__global__ __launch_bounds__(256, 1)
void lstm_fused_kernel(const float* __restrict__ x,  const float* __restrict__ Wi,
                       const float* __restrict__ Wh, const float* __restrict__ bias,
                       const float* __restrict__ aW, const float* __restrict__ ab,
                       const float* __restrict__ av,
                       ull* __restrict__ hx, ull* __restrict__ spx,
                       float* __restrict__ ctxg)
{
    __shared__ __align__(16) char smem[SMEM_BYTES];

    const int tid = threadIdx.x;
    const int w = tid >> 6;          // wave = gate index
    const int l = tid & 63;
    const int p = blockIdx.x >> 4;   // part
    const int g = blockIdx.x & 15;   // group
    const int b0 = g * BT;

    const int n = l & 15;                    // frag col (B) / C col
    const int gcol = w*256 + p*16 + n;       // global z column for this lane
    const int gb = (l>>4)*4 + w;             // owned batch (gate phase)
    const int gd = n;                        // owned h-dim (local, 0..15)

    // ---- init: pre-split B operands into register fragments --------------
    short8 BwhH[8], BwhL[8];
    #pragma unroll
    for (int ks = 0; ks < 8; ++ks) {
        U4 H, L;
        #pragma unroll
        for (int i2 = 0; i2 < 4; ++i2) {
            int k0 = ks*32 + (l>>4)*8 + i2*2;
            unsigned h0,l0,h1,l1;
            split_bf(Wh[(size_t)k0*1024 + gcol], h0, l0);
            split_bf(Wh[(size_t)(k0+1)*1024 + gcol], h1, l1);
            H.u[i2] = h0 | (h1<<16);
            L.u[i2] = l0 | (l1<<16);
        }
        BwhH[ks] = H.s; BwhL[ks] = L.s;
    }
    short8 BwiH[2], BwiL[2];
    #pragma unroll
    for (int ks = 0; ks < 2; ++ks) {
        U4 H, L;
        #pragma unroll
        for (int i2 = 0; i2 < 4; ++i2) {
            int k0 = ks*32 + (l>>4)*8 + i2*2;
            unsigned h0,l0,h1,l1;
            split_bf(Wi[(size_t)k0*1024 + gcol], h0, l0);
            split_bf(Wi[(size_t)(k0+1)*1024 + gcol], h1, l1);
            H.u[i2] = h0 | (h1<<16);
            L.u[i2] = l0 | (l1<<16);
        }
        BwiH[ks] = H.s; BwiL[ks] = L.s;
    }
    short8 BwaH[2], BwaL[2];
    #pragma unroll
    for (int j = 0; j < 2; ++j) {
        int ks = 2*w + j;     // this wave's energy k-steps
        U4 H, L;
        #pragma unroll
        for (int i2 = 0; i2 < 4; ++i2) {
            int k0 = ks*32 + (l>>4)*8 + i2*2;
            unsigned h0,l0,h1,l1;
            split_bf(aW[(size_t)k0*256 + p*16 + n], h0, l0);
            split_bf(aW[(size_t)(k0+1)*256 + p*16 + n], h1, l1);
            H.u[i2] = h0 | (h1<<16);
            L.u[i2] = l0 | (l1<<16);
        }
        BwaH[j] = H.s; BwaL[j] = L.s;
    }
    const float bb  = bias[gcol];
    const float vj  = av[p*16 + gd];
    const float abj = ab[p*16 + gd];

    // A-pack pair constants: thread packs (b,k-octet) pairs P0,P1 of 512
    const int P0 = tid*2, P1 = tid*2+1;
    const int pb0 = P0 & 15, po0 = P0 >> 4;   // octet 0..31
    const int pb1 = P1 & 15, po1 = P1 >> 4;
    // x-pack constants (threads 0..127)
    const int xb = tid & 15, xo = (tid>>4) & 7;

    float c_state = 0.f, h1v = 0.f, h2v = 0.f;
    float m_run = -1.0e30f, l_run = 0.f, ctx = 0.f;

    float* zl = (float*)(smem + Z_OF);
    float* el = (float*)(smem + E_OF);

    for (int t = 0; t < SS; ++t) {
        ull vv[16]; float va[16];
        const ull* hr = hx + (size_t)((t-1)&1)*65536 + g*4096;
        if (t > 0) {   // issue tagged h(t-1) loads early
            #pragma unroll
            for (int j = 0; j < 8; ++j) vv[j]   = cld(hr + pb0*256 + po0*8 + j);
            #pragma unroll
            for (int j = 0; j < 8; ++j) vv[8+j] = cld(hr + pb1*256 + po1*8 + j);
        }
        // ---- x-pack (overlaps h-load latency)
        if (tid < 128) {
            const float* xp = x + ((size_t)(b0+xb)*SS + t)*II + xo*8;
            float xv[8];
            *(float4*)&xv[0] = *(const float4*)xp;
            *(float4*)&xv[4] = *(const float4*)(xp+4);
            U4 H, L;
            #pragma unroll
            for (int i2=0;i2<4;++i2){
                unsigned h0,l0,h1,l1;
                split_bf(xv[2*i2],h0,l0); split_bf(xv[2*i2+1],h1,l1);
                H.u[i2]=h0|(h1<<16); L.u[i2]=l0|(l1<<16);
            }
            int wa = (xo>>2)*1024 + ((xo&3)*16 + xb)*16;
            *(short8*)(smem + X_HI + wa) = H.s;
            *(short8*)(smem + X_LO + wa) = L.s;
        }
        if (t > 0) {
            // ---- poll tags, then pack h into A frags
            unsigned need = 0xFFFFu;
            const unsigned texp = (unsigned)t;
            int it = 0;
            while (need) {
                #pragma unroll
                for (int e = 0; e < 16; ++e)
                    if (need & (1u<<e)) {
                        if ((unsigned)(vv[e]>>32) == texp) {
                            va[e] = __uint_as_float((unsigned)vv[e]);
                            need &= ~(1u<<e);
                        }
                    }
                if (!need || ++it > POLL_CAP) break;
                #pragma unroll
                for (int e = 0; e < 16; ++e)
                    if (need & (1u<<e))
                        vv[e] = cld(hr + ((e<8) ? (pb0*256+po0*8+e)
                                              : (pb1*256+po1*8+(e-8))));
            }
            U4 H0,L0,H1,L1;
            #pragma unroll
            for (int i2=0;i2<4;++i2){
                unsigned a0,b0q,c0,d0;
                split_bf(va[2*i2],a0,b0q);   split_bf(va[2*i2+1],c0,d0);
                H0.u[i2]=a0|(c0<<16); L0.u[i2]=b0q|(d0<<16);
                split_bf(va[8+2*i2],a0,b0q); split_bf(va[9+2*i2],c0,d0);
                H1.u[i2]=a0|(c0<<16); L1.u[i2]=b0q|(d0<<16);
            }
            int wa0 = (po0>>2)*1024 + ((po0&3)*16 + pb0)*16;
            int wa1 = (po1>>2)*1024 + ((po1&3)*16 + pb1)*16;
            *(short8*)(smem + A_HI + wa0) = H0.s;
            *(short8*)(smem + A_LO + wa0) = L0.s;
            *(short8*)(smem + A_HI + wa1) = H1.s;
            *(short8*)(smem + A_LO + wa1) = L1.s;
        }
        __syncthreads();

        // ---- MFMA: z = bias + x@Wi (+ h@Wh), energy partial
        f32x4 zacc = {bb,bb,bb,bb};
        #pragma unroll
        for (int ks=0; ks<2; ++ks){
            short8 ah = *(const short8*)(smem + X_HI + ks*1024 + l*16);
            short8 al = *(const short8*)(smem + X_LO + ks*1024 + l*16);
            zacc = MFMA(ah, BwiH[ks], zacc);
            zacc = MFMA(ah, BwiL[ks], zacc);
            zacc = MFMA(al, BwiH[ks], zacc);
        }
        f32x4 zacc1 = {0.f,0.f,0.f,0.f};
        f32x4 eacc  = {0.f,0.f,0.f,0.f};
        if (t > 0) {
            #pragma unroll
            for (int ks=0; ks<8; ++ks){
                short8 ah = *(const short8*)(smem + A_HI + ks*1024 + l*16);
                short8 al = *(const short8*)(smem + A_LO + ks*1024 + l*16);
                if ((ks & 1) == 0) {
                    zacc = MFMA(ah, BwhH[ks], zacc);
                    zacc = MFMA(ah, BwhL[ks], zacc);
                    zacc = MFMA(al, BwhH[ks], zacc);
                } else {
                    zacc1 = MFMA(ah, BwhH[ks], zacc1);
                    zacc1 = MFMA(ah, BwhL[ks], zacc1);
                    zacc1 = MFMA(al, BwhH[ks], zacc1);
                }
                if ((ks>>1) == w) {
                    int jj = ks & 1;
                    eacc = MFMA(ah, BwaH[jj], eacc);
                    eacc = MFMA(ah, BwaL[jj], eacc);
                    eacc = MFMA(al, BwaH[jj], eacc);
                }
            }
        }
        #pragma unroll
        for (int r=0;r<4;++r) zl[w*256 + r*64 + l] = zacc[r] + zacc1[r];
        if (t > 0) {
            #pragma unroll
            for (int r=0;r<4;++r) el[w*256 + r*64 + l] = eacc[r];
        }
        // issue sp(t-2) load early
        ull spr = 0;
        ull* spp = spx + (size_t)(t&1)*4096 + g*256 + gb*16 + gd;
        if (t > 1) spr = cld(spp);
        __syncthreads();

        // ---- gates (thread owns (gb, gd))
        float z0 = zl[0*256 + w*64 + l];
        float z1 = zl[1*256 + w*64 + l];
        float z2 = zl[2*256 + w*64 + l];
        float z3 = zl[3*256 + w*64 + l];
        float ig = fsig(z0), fg = fsig(z1), gv = ftanh(z2), og = fsig(z3);
        c_state = fg*c_state + ig*gv;
        float h = og * ftanh(c_state);

        // ---- publish h(t) tagged (critical path — first)
        cst(hx + (size_t)(t&1)*65536 + g*4096 + gb*256 + p*16 + gd,
            ((ull)(unsigned)(t+1) << 32) | (ull)__float_as_uint(h));

        // ---- online-softmax update for time t-2
        if (t > 1) {
            const unsigned texp = (unsigned)(t-1);
            int it = 0;
            while ((unsigned)(spr>>32) != texp && it++ < POLL_CAP) spr = cld(spp);
            float s = __uint_as_float((unsigned)spr);
            s += __shfl_xor(s,1); s += __shfl_xor(s,2);
            s += __shfl_xor(s,4); s += __shfl_xor(s,8);
            float m_new = fmaxf(m_run, s);
            float sc = __expf(m_run - m_new);
            float wt = __expf(s - m_new);
            l_run = l_run*sc + wt;
            ctx   = ctx*sc + wt*h2v;
            m_run = m_new;
        }
        // ---- score partial for time t-1
        if (t > 0) {
            float e = el[0*256+w*64+l] + el[1*256+w*64+l]
                    + el[2*256+w*64+l] + el[3*256+w*64+l] + abj;
            float scp = vj * ftanh(e);
            scp += __shfl_xor(scp,1); scp += __shfl_xor(scp,2);
            scp += __shfl_xor(scp,4); scp += __shfl_xor(scp,8);
            if (gd == 0)
                cst(spx + (size_t)((t-1)&1)*4096 + g*256 + gb*16 + p,
                    ((ull)(unsigned)t << 32) | (ull)__float_as_uint(scp));
        }
        h2v = h1v; h1v = h;
    }

    // ---- epilogue A: energy/score for SS-1, softmax update for SS-2 ------
    {
        ull vv[16]; float va[16];
        const ull* hr = hx + (size_t)((SS-1)&1)*65536 + g*4096;
        #pragma unroll
        for (int j = 0; j < 8; ++j) vv[j]   = cld(hr + pb0*256 + po0*8 + j);
        #pragma unroll
        for (int j = 0; j < 8; ++j) vv[8+j] = cld(hr + pb1*256 + po1*8 + j);
        unsigned need = 0xFFFFu;
        const unsigned texp = (unsigned)SS;
        int it = 0;
        while (need) {
            #pragma unroll
            for (int e = 0; e < 16; ++e)
                if (need & (1u<<e)) {
                    if ((unsigned)(vv[e]>>32) == texp) {
                        va[e] = __uint_as_float((unsigned)vv[e]);
                        need &= ~(1u<<e);
                    }
                }
            if (!need || ++it > POLL_CAP) break;
            #pragma unroll
            for (int e = 0; e < 16; ++e)
                if (need & (1u<<e))
                    vv[e] = cld(hr + ((e<8) ? (pb0*256+po0*8+e)
                                          : (pb1*256+po1*8+(e-8))));
        }
        U4 H0,L0,H1,L1;
        #pragma unroll
        for (int i2=0;i2<4;++i2){
            unsigned a0,b0q,c0,d0;
            split_bf(va[2*i2],a0,b0q);   split_bf(va[2*i2+1],c0,d0);
            H0.u[i2]=a0|(c0<<16); L0.u[i2]=b0q|(d0<<16);
            split_bf(va[8+2*i2],a0,b0q); split_bf(va[9+2*i2],c0,d0);
            H1.u[i2]=a0|(c0<<16); L1.u[i2]=b0q|(d0<<16);
        }
        int wa0 = (po0>>2)*1024 + ((po0&3)*16 + pb0)*16;
        int wa1 = (po1>>2)*1024 + ((po1&3)*16 + pb1)*16;
        *(short8*)(smem + A_HI + wa0) = H0.s;
        *(short8*)(smem + A_LO + wa0) = L0.s;
        *(short8*)(smem + A_HI + wa1) = H1.s;
        *(short8*)(smem + A_LO + wa1) = L1.s;
        __syncthreads();

        f32x4 eacc = {0.f,0.f,0.f,0.f};
        #pragma unroll
        for (int ks=0; ks<8; ++ks){
            if ((ks>>1) == w) {
                short8 ah = *(const short8*)(smem + A_HI + ks*1024 + l*16);
                short8 al = *(const short8*)(smem + A_LO + ks*1024 + l*16);
                int jj = ks & 1;
                eacc = MFMA(ah, BwaH[jj], eacc);
                eacc = MFMA(ah, BwaL[jj], eacc);
                eacc = MFMA(al, BwaH[jj], eacc);
            }
        }
        #pragma unroll
        for (int r=0;r<4;++r) el[w*256 + r*64 + l] = eacc[r];
        ull spr = 0;
        ull* spp = spx + (size_t)(SS&1)*4096 + g*256 + gb*16 + gd; // slot (SS-2)&1
        spr = cld(spp);
        __syncthreads();

        {   // softmax update for SS-2
            const unsigned te2 = (unsigned)(SS-1);
            int it2 = 0;
            while ((unsigned)(spr>>32) != te2 && it2++ < POLL_CAP) spr = cld(spp);
            float s = __uint_as_float((unsigned)spr);
            s += __shfl_xor(s,1); s += __shfl_xor(s,2);
            s += __shfl_xor(s,4); s += __shfl_xor(s,8);
            float m_new = fmaxf(m_run, s);
            float sc = __expf(m_run - m_new);
            float wt = __expf(s - m_new);
            l_run = l_run*sc + wt;
            ctx   = ctx*sc + wt*h2v;
            m_run = m_new;
        }
        h2v = h1v;
        // score for SS-1
        float e = el[0*256+w*64+l] + el[1*256+w*64+l]
                + el[2*256+w*64+l] + el[3*256+w*64+l] + abj;
        float scp = vj * ftanh(e);
        scp += __shfl_xor(scp,1); scp += __shfl_xor(scp,2);
        scp += __shfl_xor(scp,4); scp += __shfl_xor(scp,8);
        if (gd == 0)
            cst(spx + (size_t)((SS-1)&1)*4096 + g*256 + gb*16 + p,
                ((ull)(unsigned)SS << 32) | (ull)__float_as_uint(scp));
    }

    // ---- epilogue B: softmax update for SS-1, write context --------------
    {
        ull* spp = spx + (size_t)((SS-1)&1)*4096 + g*256 + gb*16 + gd;
        ull spr = cld(spp);
        const unsigned texp = (unsigned)SS;
        int it = 0;
        while ((unsigned)(spr>>32) != texp && it++ < POLL_CAP) spr = cld(spp);
        float s = __uint_as_float((unsigned)spr);
        s += __shfl_xor(s,1); s += __shfl_xor(s,2);
        s += __shfl_xor(s,4); s += __shfl_xor(s,8);
        float m_new = fmaxf(m_run, s);
        float sc = __expf(m_run - m_new);
        float wt = __expf(s - m_new);
        l_run = l_run*sc + wt;
        ctx   = ctx*sc + wt*h2v;   // h2v == h(SS-1)

        ctxg[(size_t)(b0+gb)*HH + p*16 + gd] = ctx / l_run;
    }
}

// ---------------------------------------------------------------------------
__global__ __launch_bounds__(64)
void finalize_kernel(const float* __restrict__ ctxg, const float* __restrict__ fcW,
                     const float* __restrict__ fcb, float* __restrict__ out)
{
    __shared__ float cs[HH];
    const int b = blockIdx.x, tid = threadIdx.x;
    *(float4*)&cs[tid*4] = *(const float4*)&ctxg[(size_t)b*HH + tid*4];
    __syncthreads();
    if (tid < OO) {
        float a = fcb[tid];
        #pragma unroll 8
        for (int d = 0; d < HH; ++d) a = fmaf(cs[d], fcW[d*OO + tid], a);
        out[b*OO + tid] = a;
    }
}

// ---------------------------------------------------------------------------
extern "C" void kernel_launch(void* const* d_in, const int* in_sizes, int n_in,
                              void* d_out, int out_size, void* d_ws, size_t ws_size,
                              hipStream_t stream)
{
    const float* x      = (const float*)d_in[0];
    const float* Wi     = (const float*)d_in[1];
    const float* Wh     = (const float*)d_in[2];
    const float* bias   = (const float*)d_in[3];
    const float* attn_W = (const float*)d_in[4];
    const float* attn_b = (const float*)d_in[5];
    const float* v      = (const float*)d_in[6];
    const float* fc_W   = (const float*)d_in[7];
    const float* fc_b   = (const float*)d_in[8];
    float* out = (float*)d_out;

    // workspace ~1.3 MB: tagged h ring + tagged score ring + context
    ull* hx  = (ull*)d_ws;                 // 2*16*16*256 = 131072 ull
    ull* spx = hx + 2*NG*BT*HH;            // 2*16*16*16  = 8192 ull
    float* ctxg = (float*)(spx + 2*NG*BT*16);  // 65536 floats

    lstm_fused_kernel<<<dim3(NG*NP), dim3(256), 0, stream>>>(
        x, Wi, Wh, bias, attn_W, attn_b, v, hx, spx, ctxg);
    finalize_kernel<<<dim3(BB), dim3(64), 0, stream>>>(ctxg, fc_W, fc_b, out);
}

// Round 6
// 4414.276 us; speedup vs baseline: 9.4623x; 1.2729x over previous
//
#include <hip/hip_runtime.h>

// Problem constants
#define BB 256
#define SS 1024
#define II 64
#define HH 256
#define OO 24
#define NG 16     // groups (16 batch rows each)
#define NP 16     // parts per group (64 z-cols = 16 h-dims each)
#define BT 16

typedef __attribute__((ext_vector_type(8))) short short8;
typedef __attribute__((ext_vector_type(4))) float f32x4;
typedef unsigned long long ull;

#define POLL_CAP 65536

// LDS byte offsets; total padded to 96KB to guarantee 1 block/CU
#define A_HI 0          // h hi frags  [8 kstep][64 lane][16B]
#define A_LO 8192
#define Z_OF 16384      // z  [gate q][reg r][lane]  f32   (4KB)
#define E_OF 20480      // energy partials, same layout    (4KB)
#define SMEM_BYTES 98304

#define MFMA(a,b,c) __builtin_amdgcn_mfma_f32_16x16x32_bf16(a,b,c,0,0,0)

__device__ __forceinline__ float fsig(float x)  { return 1.f/(1.f+__expf(-x)); }
__device__ __forceinline__ float ftanh(float x) { return 1.f - 2.f/(__expf(2.f*x)+1.f); }

__device__ __forceinline__ unsigned rne_bf16(float x){
    unsigned u = __float_as_uint(x);
    return (u + 0x7FFFu + ((u>>16)&1u)) >> 16;
}
__device__ __forceinline__ void split_bf(float x, unsigned &hi, unsigned &lo){
    hi = rne_bf16(x);
    lo = rne_bf16(x - __uint_as_float(hi<<16));
}

union U4 { unsigned u[4]; short8 s; };

__device__ __forceinline__ void pack8(const float* v, short8 &H, short8 &L){
    U4 h_, l_;
    #pragma unroll
    for (int i = 0; i < 4; ++i) {
        unsigned a,b,c,d;
        split_bf(v[2*i], a, b); split_bf(v[2*i+1], c, d);
        h_.u[i] = a | (c<<16);
        l_.u[i] = b | (d<<16);
    }
    H = h_.s; L = l_.s;
}

__device__ __forceinline__ ull cld(const ull* p){
    return __hip_atomic_load(p, __ATOMIC_RELAXED, __HIP_MEMORY_SCOPE_AGENT);
}
__device__ __forceinline__ void cst(ull* p, ull v){
    __hip_atomic_store(p, v, __ATOMIC_RELAXED, __HIP_MEMORY_SCOPE_AGENT);
}
__device__ __forceinline__ unsigned cldu(const unsigned* p){
    return __hip_atomic_load(p, __ATOMIC_RELAXED, __HIP_MEMORY_SCOPE_AGENT);
}
__device__ __forceinline__ void cstu(unsigned* p, unsigned v){
    __hip_atomic_store(p, v, __ATOMIC_RELAXED, __HIP_MEMORY_SCOPE_AGENT);
}
__device__ __forceinline__ void cstf(float* p, float v){
    __hip_atomic_store(p, v, __ATOMIC_RELAXED, __HIP_MEMORY_SCOPE_AGENT);
}

// ---------------------------------------------------------------------------
// Fused xW + LSTM + attention scores + online-softmax context, MFMA bf16x3.
// grid = 256 (16 groups x 16 parts), block = 256 (4 waves).
// Exchange: plain f32 h-ring + per-part monotone flags (round-3 scheme,
// proven cheap) carrying round-4's MFMA compute.
// ---------------------------------------------------------------------------
__global__ __launch_bounds__(256, 1)
void lstm_fused_kernel(const float* __restrict__ x,  const float* __restrict__ Wi,
                       const float* __restrict__ Wh, const float* __restrict__ bias,
                       const float* __restrict__ aW, const float* __restrict__ ab,
                       const float* __restrict__ av,
                       float* __restrict__ hgf, ull* __restrict__ spx,
                       unsigned* __restrict__ flags, float* __restrict__ ctxg)
{
    __shared__ __align__(16) char smem[SMEM_BYTES];
    __shared__ int sdead;

    const int tid = threadIdx.x;
    const int w = tid >> 6;          // wave = gate index
    const int l = tid & 63;
    const int p = blockIdx.x >> 4;   // part
    const int g = blockIdx.x & 15;   // group
    const int b0 = g * BT;

    if (tid == 0) sdead = 0;

    const int n = l & 15;                    // frag col (B) / C col
    const int gcol = w*256 + p*16 + n;       // global z column for this lane
    const int gb = (l>>4)*4 + w;             // owned batch (gate phase)
    const int gd = n;                        // owned h-dim (local, 0..15)

    // ---- init: pre-split B operands into register fragments --------------
    short8 BwhH[8], BwhL[8];
    #pragma unroll
    for (int ks = 0; ks < 8; ++ks) {
        U4 H, L;
        #pragma unroll
        for (int i2 = 0; i2 < 4; ++i2) {
            int k0 = ks*32 + (l>>4)*8 + i2*2;
            unsigned h0,l0,h1,l1;
            split_bf(Wh[(size_t)k0*1024 + gcol], h0, l0);
            split_bf(Wh[(size_t)(k0+1)*1024 + gcol], h1, l1);
            H.u[i2] = h0 | (h1<<16);
            L.u[i2] = l0 | (l1<<16);
        }
        BwhH[ks] = H.s; BwhL[ks] = L.s;
    }
    short8 BwiH[2], BwiL[2];
    #pragma unroll
    for (int ks = 0; ks < 2; ++ks) {
        U4 H, L;
        #pragma unroll
        for (int i2 = 0; i2 < 4; ++i2) {
            int k0 = ks*32 + (l>>4)*8 + i2*2;
            unsigned h0,l0,h1,l1;
            split_bf(Wi[(size_t)k0*1024 + gcol], h0, l0);
            split_bf(Wi[(size_t)(k0+1)*1024 + gcol], h1, l1);
            H.u[i2] = h0 | (h1<<16);
            L.u[i2] = l0 | (l1<<16);
        }
        BwiH[ks] = H.s; BwiL[ks] = L.s;
    }
    short8 BwaH[2], BwaL[2];
    #pragma unroll
    for (int j = 0; j < 2; ++j) {
        int ks = 2*w + j;     // this wave's energy k-steps
        U4 H, L;
        #pragma unroll
        for (int i2 = 0; i2 < 4; ++i2) {
            int k0 = ks*32 + (l>>4)*8 + i2*2;
            unsigned h0,l0,h1,l1;
            split_bf(aW[(size_t)k0*256 + p*16 + n], h0, l0);
            split_bf(aW[(size_t)(k0+1)*256 + p*16 + n], h1, l1);
            H.u[i2] = h0 | (h1<<16);
            L.u[i2] = l0 | (l1<<16);
        }
        BwaH[j] = H.s; BwaL[j] = L.s;
    }
    const float bb  = bias[gcol];
    const float vj  = av[p*16 + gd];
    const float abj = ab[p*16 + gd];

    // h-exchange mapping: thread loads batches pbase,pbase+1 x dim-octet po
    const int po    = tid >> 3;        // 0..31 (dim octet)
    const int pbase = (tid & 7) * 2;   // even batch
    const int wa0 = (po>>2)*1024 + ((po&3)*16 + pbase)*16;
    const int wa1 = wa0 + 16;

    // x direct-load frag addressing (per lane; same across waves)
    const int xb = l & 15;

    float c_state = 0.f, h1v = 0.f, h2v = 0.f;
    float m_run = -1.0e30f, l_run = 0.f, ctx = 0.f;

    float* zl = (float*)(smem + Z_OF);
    float* el = (float*)(smem + E_OF);
    unsigned* flagg = flags + g * NP;
    const int xoct = l >> 4;           // 0..3: frag k-octet within kstep

    for (int t = 0; t < SS; ++t) {
        // ---- x frags straight from global (no LDS), hides flag spin ------
        const float* xrow = x + ((size_t)(b0 + xb) * SS + t) * II + xoct*8;
        float xv0[8], xv1[8];
        *(float4*)&xv0[0] = *(const float4*)(xrow);
        *(float4*)&xv0[4] = *(const float4*)(xrow + 4);
        *(float4*)&xv1[0] = *(const float4*)(xrow + 32);
        *(float4*)&xv1[4] = *(const float4*)(xrow + 36);
        short8 XH0, XL0, XH1, XL1;
        pack8(xv0, XH0, XL0);
        pack8(xv1, XH1, XL1);

        f32x4 zacc = {bb,bb,bb,bb};
        zacc = MFMA(XH0, BwiH[0], zacc);
        zacc = MFMA(XH0, BwiL[0], zacc);
        zacc = MFMA(XL0, BwiH[0], zacc);
        zacc = MFMA(XH1, BwiH[1], zacc);
        zacc = MFMA(XH1, BwiL[1], zacc);
        zacc = MFMA(XL1, BwiH[1], zacc);

        // ---- acquire h(t-1): flag spin then coalesced coherent loads -----
        if (t > 0) {
            if (tid < NP && !sdead) {
                int it = 0;
                while (cldu(&flagg[tid]) < (unsigned)t) {
                    if (++it > POLL_CAP) { sdead = 1; break; }
                }
            }
        }
        __syncthreads();                                   // barrier 1

        ull spr = 0;
        ull* spp = spx + (size_t)(t&1)*4096 + g*256 + gb*16 + gd;

        if (t > 0) {
            const ull* hr = (const ull*)(hgf + (size_t)((t-1)&1)*65536) + g*2048;
            ull hv[8];
            #pragma unroll
            for (int j = 0; j < 4; ++j) hv[j]   = cld(hr + pbase*128 + po*4 + j);
            #pragma unroll
            for (int j = 0; j < 4; ++j) hv[4+j] = cld(hr + (pbase+1)*128 + po*4 + j);
            if (t > 1) spr = cld(spp);   // early tagged sp(t-2) load

            float va[16];
            #pragma unroll
            for (int j = 0; j < 4; ++j) {
                va[2*j]   = __uint_as_float((unsigned)hv[j]);
                va[2*j+1] = __uint_as_float((unsigned)(hv[j]>>32));
                va[8+2*j]   = __uint_as_float((unsigned)hv[4+j]);
                va[8+2*j+1] = __uint_as_float((unsigned)(hv[4+j]>>32));
            }
            short8 H0,L0,H1,L1;
            pack8(&va[0], H0, L0);
            pack8(&va[8], H1, L1);
            *(short8*)(smem + A_HI + wa0) = H0;
            *(short8*)(smem + A_LO + wa0) = L0;
            *(short8*)(smem + A_HI + wa1) = H1;
            *(short8*)(smem + A_LO + wa1) = L1;
        }
        __syncthreads();                                   // barrier 2

        // ---- MFMA: z += h@Wh, energy partial -----------------------------
        f32x4 zacc1 = {0.f,0.f,0.f,0.f};
        f32x4 eacc  = {0.f,0.f,0.f,0.f};
        if (t > 0) {
            #pragma unroll
            for (int ks = 0; ks < 8; ++ks) {
                short8 ah = *(const short8*)(smem + A_HI + ks*1024 + l*16);
                short8 al = *(const short8*)(smem + A_LO + ks*1024 + l*16);
                if ((ks & 1) == 0) {
                    zacc = MFMA(ah, BwhH[ks], zacc);
                    zacc = MFMA(ah, BwhL[ks], zacc);
                    zacc = MFMA(al, BwhH[ks], zacc);
                } else {
                    zacc1 = MFMA(ah, BwhH[ks], zacc1);
                    zacc1 = MFMA(ah, BwhL[ks], zacc1);
                    zacc1 = MFMA(al, BwhH[ks], zacc1);
                }
                if ((ks>>1) == w) {
                    int jj = ks & 1;
                    eacc = MFMA(ah, BwaH[jj], eacc);
                    eacc = MFMA(ah, BwaL[jj], eacc);
                    eacc = MFMA(al, BwaH[jj], eacc);
                }
            }
        }
        #pragma unroll
        for (int r = 0; r < 4; ++r) zl[w*256 + r*64 + l] = zacc[r] + zacc1[r];
        if (t > 0) {
            #pragma unroll
            for (int r = 0; r < 4; ++r) el[w*256 + r*64 + l] = eacc[r];
        }
        __syncthreads();                                   // barrier 3

        // ---- gates -------------------------------------------------------
        float z0 = zl[0*256 + w*64 + l];
        float z1 = zl[1*256 + w*64 + l];
        float z2 = zl[2*256 + w*64 + l];
        float z3 = zl[3*256 + w*64 + l];
        float ig = fsig(z0), fg = fsig(z1), gv = ftanh(z2), og = fsig(z3);
        c_state = fg*c_state + ig*gv;
        float h = og * ftanh(c_state);

        // ---- publish h(t), drain, release flag (critical path first) ----
        cstf(hgf + (size_t)(t&1)*65536 + g*4096 + gb*256 + p*16 + gd, h);
        asm volatile("s_waitcnt vmcnt(0)" ::: "memory");
        __syncthreads();                                   // barrier 4
        if (tid == 0) cstu(&flagg[p], (unsigned)(t + 1));

        // ---- off critical path: softmax update t-2, score partial t-1 ----
        if (t > 1) {
            const unsigned texp = (unsigned)(t-1);
            int it = 0;
            while ((unsigned)(spr>>32) != texp && it++ < POLL_CAP) spr = cld(spp);
            float s = __uint_as_float((unsigned)spr);
            s += __shfl_xor(s,1); s += __shfl_xor(s,2);
            s += __shfl_xor(s,4); s += __shfl_xor(s,8);
            float m_new = fmaxf(m_run, s);
            float sc = __expf(m_run - m_new);
            float wt = __expf(s - m_new);
            l_run = l_run*sc + wt;
            ctx   = ctx*sc + wt*h2v;
            m_run = m_new;
        }
        if (t > 0) {
            float e = el[0*256+w*64+l] + el[1*256+w*64+l]
                    + el[2*256+w*64+l] + el[3*256+w*64+l] + abj;
            float scp = vj * ftanh(e);
            scp += __shfl_xor(scp,1); scp += __shfl_xor(scp,2);
            scp += __shfl_xor(scp,4); scp += __shfl_xor(scp,8);
            if (gd == 0)
                cst(spx + (size_t)((t-1)&1)*4096 + g*256 + gb*16 + p,
                    ((ull)(unsigned)t << 32) | (ull)__float_as_uint(scp));
        }
        h2v = h1v; h1v = h;
    }

    // ---- epilogue A: energy/score for SS-1, softmax update for SS-2 ------
    {
        if (tid < NP && !sdead) {
            int it = 0;
            while (cldu(&flagg[tid]) < (unsigned)SS) {
                if (++it > POLL_CAP) { sdead = 1; break; }
            }
        }
        __syncthreads();

        const ull* hr = (const ull*)(hgf + (size_t)((SS-1)&1)*65536) + g*2048;
        ull hv[8];
        #pragma unroll
        for (int j = 0; j < 4; ++j) hv[j]   = cld(hr + pbase*128 + po*4 + j);
        #pragma unroll
        for (int j = 0; j < 4; ++j) hv[4+j] = cld(hr + (pbase+1)*128 + po*4 + j);
        float va[16];
        #pragma unroll
        for (int j = 0; j < 4; ++j) {
            va[2*j]     = __uint_as_float((unsigned)hv[j]);
            va[2*j+1]   = __uint_as_float((unsigned)(hv[j]>>32));
            va[8+2*j]   = __uint_as_float((unsigned)hv[4+j]);
            va[8+2*j+1] = __uint_as_float((unsigned)(hv[4+j]>>32));
        }
        short8 H0,L0,H1,L1;
        pack8(&va[0], H0, L0);
        pack8(&va[8], H1, L1);
        *(short8*)(smem + A_HI + wa0) = H0;
        *(short8*)(smem + A_LO + wa0) = L0;
        *(short8*)(smem + A_HI + wa1) = H1;
        *(short8*)(smem + A_LO + wa1) = L1;
        __syncthreads();

        f32x4 eacc = {0.f,0.f,0.f,0.f};
        #pragma unroll
        for (int ks = 0; ks < 8; ++ks) {
            if ((ks>>1) == w) {
                short8 ah = *(const short8*)(smem + A_HI + ks*1024 + l*16);
                short8 al = *(const short8*)(smem + A_LO + ks*1024 + l*16);
                int jj = ks & 1;
                eacc = MFMA(ah, BwaH[jj], eacc);
                eacc = MFMA(ah, BwaL[jj], eacc);
                eacc = MFMA(al, BwaH[jj], eacc);
            }
        }
        #pragma unroll
        for (int r = 0; r < 4; ++r) el[w*256 + r*64 + l] = eacc[r];
        __syncthreads();

        {   // softmax update for SS-2 (sp tagged SS-1, slot (SS-2)&1 == SS&1)
            ull* spp = spx + (size_t)(SS&1)*4096 + g*256 + gb*16 + gd;
            ull spr = cld(spp);
            const unsigned texp = (unsigned)(SS-1);
            int it = 0;
            while ((unsigned)(spr>>32) != texp && it++ < POLL_CAP) spr = cld(spp);
            float s = __uint_as_float((unsigned)spr);
            s += __shfl_xor(s,1); s += __shfl_xor(s,2);
            s += __shfl_xor(s,4); s += __shfl_xor(s,8);
            float m_new = fmaxf(m_run, s);
            float sc = __expf(m_run - m_new);
            float wt = __expf(s - m_new);
            l_run = l_run*sc + wt;
            ctx   = ctx*sc + wt*h2v;
            m_run = m_new;
        }
        h2v = h1v;
        // score for SS-1 (tag SS)
        float e = el[0*256+w*64+l] + el[1*256+w*64+l]
                + el[2*256+w*64+l] + el[3*256+w*64+l] + abj;
        float scp = vj * ftanh(e);
        scp += __shfl_xor(scp,1); scp += __shfl_xor(scp,2);
        scp += __shfl_xor(scp,4); scp += __shfl_xor(scp,8);
        if (gd == 0)
            cst(spx + (size_t)((SS-1)&1)*4096 + g*256 + gb*16 + p,
                ((ull)(unsigned)SS << 32) | (ull)__float_as_uint(scp));
    }

    // ---- epilogue B: softmax update for SS-1, write context --------------
    {
        ull* spp = spx + (size_t)((SS-1)&1)*4096 + g*256 + gb*16 + gd;
        ull spr = cld(spp);
        const unsigned texp = (unsigned)SS;
        int it = 0;
        while ((unsigned)(spr>>32) != texp && it++ < POLL_CAP) spr = cld(spp);
        float s = __uint_as_float((unsigned)spr);
        s += __shfl_xor(s,1); s += __shfl_xor(s,2);
        s += __shfl_xor(s,4); s += __shfl_xor(s,8);
        float m_new = fmaxf(m_run, s);
        float sc = __expf(m_run - m_new);
        float wt = __expf(s - m_new);
        l_run = l_run*sc + wt;
        ctx   = ctx*sc + wt*h2v;   // h2v == h(SS-1)

        ctxg[(size_t)(b0+gb)*HH + p*16 + gd] = ctx / l_run;
    }
}

// ---------------------------------------------------------------------------
__global__ __launch_bounds__(64)
void finalize_kernel(const float* __restrict__ ctxg, const float* __restrict__ fcW,
                     const float* __restrict__ fcb, float* __restrict__ out)
{
    __shared__ float cs[HH];
    const int b = blockIdx.x, tid = threadIdx.x;
    *(float4*)&cs[tid*4] = *(const float4*)&ctxg[(size_t)b*HH + tid*4];
    __syncthreads();
    if (tid < OO) {
        float a = fcb[tid];
        #pragma unroll 8
        for (int d = 0; d < HH; ++d) a = fmaf(cs[d], fcW[d*OO + tid], a);
        out[b*OO + tid] = a;
    }
}

// ---------------------------------------------------------------------------
extern "C" void kernel_launch(void* const* d_in, const int* in_sizes, int n_in,
                              void* d_out, int out_size, void* d_ws, size_t ws_size,
                              hipStream_t stream)
{
    const float* x      = (const float*)d_in[0];
    const float* Wi     = (const float*)d_in[1];
    const float* Wh     = (const float*)d_in[2];
    const float* bias   = (const float*)d_in[3];
    const float* attn_W = (const float*)d_in[4];
    const float* attn_b = (const float*)d_in[5];
    const float* v      = (const float*)d_in[6];
    const float* fc_W   = (const float*)d_in[7];
    const float* fc_b   = (const float*)d_in[8];
    float* out = (float*)d_out;

    // workspace ~850KB: h ring (plain f32) + tagged sp ring + flags + ctx
    float* hgf = (float*)d_ws;                       // 2*16*16*256 = 131072 f
    ull*   spx = (ull*)(hgf + 131072);               // 2*16*16*16  = 8192 ull
    unsigned* flags = (unsigned*)(spx + 8192);       // 256 uints
    float* ctxg = (float*)(flags + 256);             // 65536 floats

    // zero sp tags + flags each launch (kills cross-replay stale tags)
    hipMemsetAsync(spx, 0, 8192*sizeof(ull) + 256*sizeof(unsigned), stream);

    lstm_fused_kernel<<<dim3(NG*NP), dim3(256), 0, stream>>>(
        x, Wi, Wh, bias, attn_W, attn_b, v, hgf, spx, flags, ctxg);
    finalize_kernel<<<dim3(BB), dim3(64), 0, stream>>>(ctxg, fc_W, fc_b, out);
}